// Round 1
// baseline (4784.446 us; speedup 1.0000x reference)
//
#include <hip/hip_runtime.h>
#include <hip/hip_bf16.h>

#define NNODES 50000
#define EMBD   128
#define PROJD  768
#define HID    256
#define NREL   16
#define NEDGE  400000
#define BN_EPS 1e-5f
#define M_REAL NNODES
#define M_TILES 391            /* ceil(50000/128) */
#define M_PAD  (M_TILES*128)   /* 50048 */

typedef __attribute__((ext_vector_type(8))) short short8;
typedef __attribute__((ext_vector_type(4))) float f4;

__device__ __forceinline__ float bf2f(unsigned short u) {
    union { unsigned int i; float f; } x; x.i = ((unsigned int)u) << 16; return x.f;
}
__device__ __forceinline__ unsigned short f2bf(float f) {
    __hip_bfloat16 h = __float2bfloat16(f);
    union { __hip_bfloat16 h; unsigned short u; } x; x.h = h; return x.u;
}

// ---------------------------------------------------------------------------
// GEMM: C[M,N] = A[M,K](bf16) @ W^T[N,K](bf16)   (+bias) (+agg, fp32 out, BN sums)
// 128x128 tile, 4 waves (2x2), each wave 4x4 grid of 16x16x32 MFMAs.
// No LDS: fragments loaded straight from global (lane-contiguous 16B loads).
// A-frag: A[m=lane&15][k=quad*8+j]; B-frag: W^T[n=lane&15][k=quad*8+j];
// C/D:    col=lane&15, row=quad*4+reg   (guide-verified layouts, m89/m91)
// ---------------------------------------------------------------------------
template<int K, int N, bool BIAS, bool ROOT>
__global__ __launch_bounds__(256) void gemm_k(
    const unsigned short* __restrict__ A,
    const unsigned short* __restrict__ WT,
    const float* __restrict__ bias,
    const float* __restrict__ agg,
    float* __restrict__ bnsum,
    void* __restrict__ outv)
{
    static_assert(!ROOT || N == 256, "ROOT mode assumes N==256");
    const int tile_n = blockIdx.x * 128;
    const int tile_m = blockIdx.y * 128;
    const int wave = threadIdx.x >> 6;
    const int lane = threadIdx.x & 63;
    const int wm = (wave & 1) << 6;
    const int wn = (wave >> 1) << 6;
    const int lm = lane & 15;
    const int kq = lane >> 4;

    const unsigned short* ap[4];
    const unsigned short* bp[4];
#pragma unroll
    for (int mi = 0; mi < 4; ++mi) {
        int r = tile_m + wm + mi * 16 + lm;
        if (r >= M_REAL) r = M_REAL - 1;          // clamp: pad rows never fetched
        ap[mi] = A + (size_t)r * K + kq * 8;
    }
#pragma unroll
    for (int ni = 0; ni < 4; ++ni) {
        int c = tile_n + wn + ni * 16 + lm;       // N % 128 == 0, always valid
        bp[ni] = WT + (size_t)c * K + kq * 8;
    }

    f4 acc[4][4];
#pragma unroll
    for (int mi = 0; mi < 4; ++mi)
#pragma unroll
        for (int ni = 0; ni < 4; ++ni) acc[mi][ni] = (f4){0.f, 0.f, 0.f, 0.f};

    for (int k0 = 0; k0 < K; k0 += 32) {
        short8 af[4], bfr[4];
#pragma unroll
        for (int mi = 0; mi < 4; ++mi) af[mi] = *(const short8*)(ap[mi] + k0);
#pragma unroll
        for (int ni = 0; ni < 4; ++ni) bfr[ni] = *(const short8*)(bp[ni] + k0);
#pragma unroll
        for (int mi = 0; mi < 4; ++mi)
#pragma unroll
            for (int ni = 0; ni < 4; ++ni)
                acc[mi][ni] = __builtin_amdgcn_mfma_f32_16x16x32_bf16(
                    af[mi], bfr[ni], acc[mi][ni], 0, 0, 0);
    }

    int cols[4]; float bv[4];
#pragma unroll
    for (int ni = 0; ni < 4; ++ni) {
        cols[ni] = tile_n + wn + ni * 16 + lm;
        bv[ni] = BIAS ? bias[cols[ni]] : 0.f;
    }

    if (!ROOT) {
        unsigned short* O = (unsigned short*)outv;
#pragma unroll
        for (int mi = 0; mi < 4; ++mi) {
#pragma unroll
            for (int rg = 0; rg < 4; ++rg) {
                int row = tile_m + wm + mi * 16 + kq * 4 + rg;
                if (row < M_REAL) {
                    size_t base = (size_t)row * N;
#pragma unroll
                    for (int ni = 0; ni < 4; ++ni)
                        O[base + cols[ni]] = f2bf(acc[mi][ni][rg] + bv[ni]);
                }
            }
        }
    } else {
        float* O = (float*)outv;
        float s1[4] = {0.f, 0.f, 0.f, 0.f}, s2[4] = {0.f, 0.f, 0.f, 0.f};
#pragma unroll
        for (int mi = 0; mi < 4; ++mi) {
#pragma unroll
            for (int rg = 0; rg < 4; ++rg) {
                int row = tile_m + wm + mi * 16 + kq * 4 + rg;
                if (row < M_REAL) {
                    size_t base = (size_t)row * 256;
#pragma unroll
                    for (int ni = 0; ni < 4; ++ni) {
                        float v = acc[mi][ni][rg] + bv[ni] + agg[base + cols[ni]];
                        O[base + cols[ni]] = v;
                        s1[ni] += v; s2[ni] += v * v;
                    }
                }
            }
        }
#pragma unroll
        for (int ni = 0; ni < 4; ++ni) {
            float a = s1[ni], b = s2[ni];
            a += __shfl_xor(a, 16); a += __shfl_xor(a, 32);
            b += __shfl_xor(b, 16); b += __shfl_xor(b, 32);
            if (lane < 16) {
                atomicAdd(&bnsum[cols[ni]], a);
                atomicAdd(&bnsum[256 + cols[ni]], b);
            }
        }
    }
}

// row L2-normalize emb -> bf16 x0. One wave per node (128 cols = 2/lane).
__global__ __launch_bounds__(256) void norm_k(const float* __restrict__ emb,
                                              unsigned short* __restrict__ x0)
{
    int node = blockIdx.x * 4 + (threadIdx.x >> 6);
    int lane = threadIdx.x & 63;
    const float2* p = (const float2*)(emb + (size_t)node * EMBD);
    float2 v = p[lane];
    float ss = v.x * v.x + v.y * v.y;
#pragma unroll
    for (int o = 32; o > 0; o >>= 1) ss += __shfl_xor(ss, o);
    float inv = 1.f / fmaxf(sqrtf(ss), 1e-12f);
    unsigned int pack = (unsigned int)f2bf(v.x * inv) | ((unsigned int)f2bf(v.y * inv) << 16);
    ((unsigned int*)(x0 + (size_t)node * EMBD))[lane] = pack;
}

__global__ void cnt_k(const int* __restrict__ ei, const int* __restrict__ et,
                      unsigned int* __restrict__ cnt)
{
    int e = blockIdx.x * 256 + threadIdx.x;
    if (e >= NEDGE) return;
    atomicAdd(&cnt[(size_t)ei[NEDGE + e] * NREL + et[e]], 1u);
}

__global__ void dinv_k(const int* __restrict__ ei, const int* __restrict__ et,
                       const unsigned int* __restrict__ cnt, float* __restrict__ dinv)
{
    int e = blockIdx.x * 256 + threadIdx.x;
    if (e >= NEDGE) return;
    unsigned int c = cnt[(size_t)ei[NEDGE + e] * NREL + et[e]];
    dinv[e] = 1.f / (float)(c ? c : 1u);
}

// transpose+convert: in[K,N] f32 -> out[N,K] bf16. grid(ceil(N/256), K)
__global__ void trans_k(const float* __restrict__ in, unsigned short* __restrict__ out,
                        int K, int N)
{
    int n = blockIdx.x * 256 + threadIdx.x;
    int k = blockIdx.y;
    if (n < N) out[(size_t)n * K + k] = f2bf(in[(size_t)k * N + n]);
}

// one wave per edge: msg = (c0*dinv)*h0[src] + (c1*dinv)*h1[src]; atomicAdd into agg[dst]
__global__ __launch_bounds__(256) void scatter_k(
    const unsigned short* __restrict__ h, const float* __restrict__ comp,
    const int* __restrict__ ei, const int* __restrict__ et,
    const float* __restrict__ dinv, float* __restrict__ agg)
{
    int e = blockIdx.x * 4 + (threadIdx.x >> 6);
    int lane = threadIdx.x & 63;
    int src = ei[e], dst = ei[NEDGE + e];
    int t = et[e];
    float di = dinv[e];
    float w0 = comp[t * 2] * di, w1 = comp[t * 2 + 1] * di;
    const ushort4* hp = (const ushort4*)(h + (size_t)src * 512 + lane * 4);
    ushort4 u0 = hp[0];
    ushort4 u1 = hp[64];   // +256 elements (basis 1)
    float* ag = agg + (size_t)dst * 256 + lane * 4;
    atomicAdd(ag + 0, w0 * bf2f(u0.x) + w1 * bf2f(u1.x));
    atomicAdd(ag + 1, w0 * bf2f(u0.y) + w1 * bf2f(u1.y));
    atomicAdd(ag + 2, w0 * bf2f(u0.z) + w1 * bf2f(u1.z));
    atomicAdd(ag + 3, w0 * bf2f(u0.w) + w1 * bf2f(u1.w));
}

__global__ void bnfin_k(const float* __restrict__ bnsum, const float* __restrict__ gamma,
                        const float* __restrict__ beta, float* __restrict__ bnss)
{
    int c = threadIdx.x;
    float mu = bnsum[c] * (1.f / M_REAL);
    float var = bnsum[256 + c] * (1.f / M_REAL) - mu * mu;
    var = fmaxf(var, 0.f);
    float inv = rsqrtf(var + BN_EPS);
    float sc = gamma[c] * inv;
    bnss[c] = sc;
    bnss[256 + c] = beta[c] - mu * sc;
}

// y(fp32) -> BN scale/shift + relu -> bf16 x_next (or fp32 d_out for last layer)
template<bool LAST>
__global__ __launch_bounds__(256) void apply_k(const float* __restrict__ y,
                                               const float* __restrict__ bnss,
                                               unsigned short* __restrict__ xn,
                                               float* __restrict__ outp)
{
    int i = blockIdx.x * 256 + threadIdx.x;  // 4 elements per thread
    int row = i >> 6;
    int c4 = (i & 63) * 4;
    f4 v = *(const f4*)(y + (size_t)row * 256 + c4);
    f4 sc = *(const f4*)(bnss + c4);
    f4 sh = *(const f4*)(bnss + 256 + c4);
    f4 r;
    r.x = fmaxf(v.x * sc.x + sh.x, 0.f);
    r.y = fmaxf(v.y * sc.y + sh.y, 0.f);
    r.z = fmaxf(v.z * sc.z + sh.z, 0.f);
    r.w = fmaxf(v.w * sc.w + sh.w, 0.f);
    if (LAST) {
        *(f4*)(outp + (size_t)row * 256 + c4) = r;
    } else {
        ushort4 u;
        u.x = f2bf(r.x); u.y = f2bf(r.y); u.z = f2bf(r.z); u.w = f2bf(r.w);
        *(ushort4*)(xn + (size_t)row * 256 + c4) = u;
    }
}

extern "C" void kernel_launch(void* const* d_in, const int* in_sizes, int n_in,
                              void* d_out, int out_size, void* d_ws, size_t ws_size,
                              hipStream_t stream)
{
    const int*   edge_index = (const int*)d_in[0];
    const int*   edge_type  = (const int*)d_in[1];
    const float* emb    = (const float*)d_in[2];
    const float* proj_w = (const float*)d_in[3];
    const float* proj_b = (const float*)d_in[4];
    const float* comp[3]  = {(const float*)d_in[5],  (const float*)d_in[11], (const float*)d_in[17]};
    const float* bases[3] = {(const float*)d_in[6],  (const float*)d_in[12], (const float*)d_in[18]};
    const float* root[3]  = {(const float*)d_in[7],  (const float*)d_in[13], (const float*)d_in[19]};
    const float* biasp[3] = {(const float*)d_in[8],  (const float*)d_in[14], (const float*)d_in[20]};
    const float* gamma[3] = {(const float*)d_in[9],  (const float*)d_in[15], (const float*)d_in[21]};
    const float* beta[3]  = {(const float*)d_in[10], (const float*)d_in[16], (const float*)d_in[22]};

    char* ws = (char*)d_ws;
    size_t off = 0;
    auto alloc = [&](size_t bytes) -> char* {
        char* p = ws + off;
        off = (off + bytes + 255) & ~(size_t)255;
        return p;
    };

    unsigned short* xP  = (unsigned short*)alloc((size_t)M_PAD * 768 * 2);  // proj out; reused as x2
    unsigned short* x1  = (unsigned short*)alloc((size_t)M_PAD * 256 * 2);
    unsigned short* h   = (unsigned short*)alloc((size_t)M_PAD * 512 * 2);  // also y (f32, same bytes)
    float*          agg = (float*)alloc((size_t)M_REAL * 256 * 4);          // x0 aliased inside
    unsigned int*   cnt = (unsigned int*)alloc((size_t)M_REAL * NREL * 4);
    float*          dnv = (float*)alloc((size_t)NEDGE * 4);
    unsigned short* wTproj = (unsigned short*)alloc((size_t)768 * 128 * 2);
    unsigned short* wTb0 = (unsigned short*)alloc((size_t)512 * 768 * 2);
    unsigned short* wTr0 = (unsigned short*)alloc((size_t)256 * 768 * 2);
    unsigned short* wTb1 = (unsigned short*)alloc((size_t)512 * 256 * 2);
    unsigned short* wTr1 = (unsigned short*)alloc((size_t)256 * 256 * 2);
    unsigned short* wTb2 = (unsigned short*)alloc((size_t)512 * 256 * 2);
    unsigned short* wTr2 = (unsigned short*)alloc((size_t)256 * 256 * 2);
    float* bns  = (float*)alloc(3 * 512 * 4);  // sums (zeroed)
    float* bnss = (float*)alloc(3 * 512 * 4);  // scale/shift

    unsigned short* x0 = (unsigned short*)agg;  // alias: x0 dead before agg zeroed
    unsigned short* x2 = xP;                    // alias: xP dead before x2 written
    float* y = (float*)h;                       // alias: h dead before y written

    hipMemsetAsync(cnt, 0, (size_t)M_REAL * NREL * 4, stream);
    hipMemsetAsync(bns, 0, 3 * 512 * 4, stream);

    norm_k<<<M_REAL / 4, 256, 0, stream>>>(emb, x0);
    cnt_k<<<(NEDGE + 255) / 256, 256, 0, stream>>>(edge_index, edge_type, cnt);
    dinv_k<<<(NEDGE + 255) / 256, 256, 0, stream>>>(edge_index, edge_type, cnt, dnv);

    trans_k<<<dim3(3, 128), 256, 0, stream>>>(proj_w, wTproj, 128, 768);
    trans_k<<<dim3(1, 768), 256, 0, stream>>>(bases[0],           wTb0,            768, 256);
    trans_k<<<dim3(1, 768), 256, 0, stream>>>(bases[0] + 768*256, wTb0 + 256*768,  768, 256);
    trans_k<<<dim3(1, 768), 256, 0, stream>>>(root[0],            wTr0,            768, 256);
    trans_k<<<dim3(1, 256), 256, 0, stream>>>(bases[1],           wTb1,            256, 256);
    trans_k<<<dim3(1, 256), 256, 0, stream>>>(bases[1] + 256*256, wTb1 + 256*256,  256, 256);
    trans_k<<<dim3(1, 256), 256, 0, stream>>>(root[1],            wTr1,            256, 256);
    trans_k<<<dim3(1, 256), 256, 0, stream>>>(bases[2],           wTb2,            256, 256);
    trans_k<<<dim3(1, 256), 256, 0, stream>>>(bases[2] + 256*256, wTb2 + 256*256,  256, 256);
    trans_k<<<dim3(1, 256), 256, 0, stream>>>(root[2],            wTr2,            256, 256);

    // projection: [50000,128] @ [128,768] + b
    gemm_k<128, 768, true, false><<<dim3(6, M_TILES), 256, 0, stream>>>(
        x0, wTproj, proj_b, nullptr, nullptr, xP);

    // ---- layer 0 (d_in = 768) ----
    gemm_k<768, 512, false, false><<<dim3(4, M_TILES), 256, 0, stream>>>(
        xP, wTb0, nullptr, nullptr, nullptr, h);
    hipMemsetAsync(agg, 0, (size_t)M_REAL * 256 * 4, stream);
    scatter_k<<<NEDGE / 4, 256, 0, stream>>>(h, comp[0], edge_index, edge_type, dnv, agg);
    gemm_k<768, 256, true, true><<<dim3(2, M_TILES), 256, 0, stream>>>(
        xP, wTr0, biasp[0], agg, bns + 0 * 512, y);
    bnfin_k<<<1, 256, 0, stream>>>(bns + 0 * 512, gamma[0], beta[0], bnss + 0 * 512);
    apply_k<false><<<(M_REAL * 64) / 256, 256, 0, stream>>>(y, bnss + 0 * 512, x1, nullptr);

    // ---- layer 1 (d_in = 256) ----
    gemm_k<256, 512, false, false><<<dim3(4, M_TILES), 256, 0, stream>>>(
        x1, wTb1, nullptr, nullptr, nullptr, h);
    hipMemsetAsync(agg, 0, (size_t)M_REAL * 256 * 4, stream);
    scatter_k<<<NEDGE / 4, 256, 0, stream>>>(h, comp[1], edge_index, edge_type, dnv, agg);
    gemm_k<256, 256, true, true><<<dim3(2, M_TILES), 256, 0, stream>>>(
        x1, wTr1, biasp[1], agg, bns + 1 * 512, y);
    bnfin_k<<<1, 256, 0, stream>>>(bns + 1 * 512, gamma[1], beta[1], bnss + 1 * 512);
    apply_k<false><<<(M_REAL * 64) / 256, 256, 0, stream>>>(y, bnss + 1 * 512, x2, nullptr);

    // ---- layer 2 (d_in = 256) ----
    gemm_k<256, 512, false, false><<<dim3(4, M_TILES), 256, 0, stream>>>(
        x2, wTb2, nullptr, nullptr, nullptr, h);
    hipMemsetAsync(agg, 0, (size_t)M_REAL * 256 * 4, stream);
    scatter_k<<<NEDGE / 4, 256, 0, stream>>>(h, comp[2], edge_index, edge_type, dnv, agg);
    gemm_k<256, 256, true, true><<<dim3(2, M_TILES), 256, 0, stream>>>(
        x2, wTr2, biasp[2], agg, bns + 2 * 512, y);
    bnfin_k<<<1, 256, 0, stream>>>(bns + 2 * 512, gamma[2], beta[2], bnss + 2 * 512);
    apply_k<true><<<(M_REAL * 64) / 256, 256, 0, stream>>>(y, bnss + 2 * 512, nullptr, (float*)d_out);
}

// Round 2
// 1037.539 us; speedup vs baseline: 4.6113x; 4.6113x over previous
//
#include <hip/hip_runtime.h>
#include <hip/hip_bf16.h>

#define NNODES 50000
#define EMBD   128
#define PROJD  768
#define HID    256
#define NREL   16
#define NEDGE  400000
#define BN_EPS 1e-5f
#define M_REAL NNODES
#define M_TILES 391            /* ceil(50000/128) */
#define M_PAD  (M_TILES*128)   /* 50048 */
#define SCAN_B 512
#define SCAN_NB ((NNODES + SCAN_B - 1) / SCAN_B)   /* 98 */

typedef __attribute__((ext_vector_type(8))) short short8;
typedef __attribute__((ext_vector_type(4))) float f4;

__device__ __forceinline__ float bf2f(unsigned short u) {
    union { unsigned int i; float f; } x; x.i = ((unsigned int)u) << 16; return x.f;
}
__device__ __forceinline__ unsigned short f2bf(float f) {
    __hip_bfloat16 h = __float2bfloat16(f);
    union { __hip_bfloat16 h; unsigned short u; } x; x.h = h; return x.u;
}

// ---------------------------------------------------------------------------
// GEMM: C[M,N] = A[M,K](bf16) @ W^T[N,K](bf16)   (+bias) (+agg, fp32 out, BN sums)
// 128x128 tile, 4 waves (2x2), each wave 4x4 grid of 16x16x32 MFMAs.
// No LDS: fragments loaded straight from global (lane-contiguous 16B loads).
// ---------------------------------------------------------------------------
template<int K, int N, bool BIAS, bool ROOT>
__global__ __launch_bounds__(256) void gemm_k(
    const unsigned short* __restrict__ A,
    const unsigned short* __restrict__ WT,
    const float* __restrict__ bias,
    const float* __restrict__ agg,
    float* __restrict__ bnsum,
    void* __restrict__ outv)
{
    static_assert(!ROOT || N == 256, "ROOT mode assumes N==256");
    const int tile_n = blockIdx.x * 128;
    const int tile_m = blockIdx.y * 128;
    const int wave = threadIdx.x >> 6;
    const int lane = threadIdx.x & 63;
    const int wm = (wave & 1) << 6;
    const int wn = (wave >> 1) << 6;
    const int lm = lane & 15;
    const int kq = lane >> 4;

    const unsigned short* ap[4];
    const unsigned short* bp[4];
#pragma unroll
    for (int mi = 0; mi < 4; ++mi) {
        int r = tile_m + wm + mi * 16 + lm;
        if (r >= M_REAL) r = M_REAL - 1;          // clamp: pad rows never fetched
        ap[mi] = A + (size_t)r * K + kq * 8;
    }
#pragma unroll
    for (int ni = 0; ni < 4; ++ni) {
        int c = tile_n + wn + ni * 16 + lm;       // N % 128 == 0, always valid
        bp[ni] = WT + (size_t)c * K + kq * 8;
    }

    f4 acc[4][4];
#pragma unroll
    for (int mi = 0; mi < 4; ++mi)
#pragma unroll
        for (int ni = 0; ni < 4; ++ni) acc[mi][ni] = (f4){0.f, 0.f, 0.f, 0.f};

    for (int k0 = 0; k0 < K; k0 += 32) {
        short8 af[4], bfr[4];
#pragma unroll
        for (int mi = 0; mi < 4; ++mi) af[mi] = *(const short8*)(ap[mi] + k0);
#pragma unroll
        for (int ni = 0; ni < 4; ++ni) bfr[ni] = *(const short8*)(bp[ni] + k0);
#pragma unroll
        for (int mi = 0; mi < 4; ++mi)
#pragma unroll
            for (int ni = 0; ni < 4; ++ni)
                acc[mi][ni] = __builtin_amdgcn_mfma_f32_16x16x32_bf16(
                    af[mi], bfr[ni], acc[mi][ni], 0, 0, 0);
    }

    int cols[4]; float bv[4];
#pragma unroll
    for (int ni = 0; ni < 4; ++ni) {
        cols[ni] = tile_n + wn + ni * 16 + lm;
        bv[ni] = BIAS ? bias[cols[ni]] : 0.f;
    }

    if (!ROOT) {
        unsigned short* O = (unsigned short*)outv;
#pragma unroll
        for (int mi = 0; mi < 4; ++mi) {
#pragma unroll
            for (int rg = 0; rg < 4; ++rg) {
                int row = tile_m + wm + mi * 16 + kq * 4 + rg;
                if (row < M_REAL) {
                    size_t base = (size_t)row * N;
#pragma unroll
                    for (int ni = 0; ni < 4; ++ni)
                        O[base + cols[ni]] = f2bf(acc[mi][ni][rg] + bv[ni]);
                }
            }
        }
    } else {
        float* O = (float*)outv;
        float s1[4] = {0.f, 0.f, 0.f, 0.f}, s2[4] = {0.f, 0.f, 0.f, 0.f};
#pragma unroll
        for (int mi = 0; mi < 4; ++mi) {
#pragma unroll
            for (int rg = 0; rg < 4; ++rg) {
                int row = tile_m + wm + mi * 16 + kq * 4 + rg;
                if (row < M_REAL) {
                    size_t base = (size_t)row * 256;
#pragma unroll
                    for (int ni = 0; ni < 4; ++ni) {
                        float v = acc[mi][ni][rg] + bv[ni] + agg[base + cols[ni]];
                        O[base + cols[ni]] = v;
                        s1[ni] += v; s2[ni] += v * v;
                    }
                }
            }
        }
#pragma unroll
        for (int ni = 0; ni < 4; ++ni) {
            float a = s1[ni], b = s2[ni];
            a += __shfl_xor(a, 16); a += __shfl_xor(a, 32);
            b += __shfl_xor(b, 16); b += __shfl_xor(b, 32);
            if (lane < 16) {
                atomicAdd(&bnsum[cols[ni]], a);
                atomicAdd(&bnsum[256 + cols[ni]], b);
            }
        }
    }
}

// row L2-normalize emb -> bf16 x0. One wave per node (128 cols = 2/lane).
__global__ __launch_bounds__(256) void norm_k(const float* __restrict__ emb,
                                              unsigned short* __restrict__ x0)
{
    int node = blockIdx.x * 4 + (threadIdx.x >> 6);
    int lane = threadIdx.x & 63;
    const float2* p = (const float2*)(emb + (size_t)node * EMBD);
    float2 v = p[lane];
    float ss = v.x * v.x + v.y * v.y;
#pragma unroll
    for (int o = 32; o > 0; o >>= 1) ss += __shfl_xor(ss, o);
    float inv = 1.f / fmaxf(sqrtf(ss), 1e-12f);
    unsigned int pack = (unsigned int)f2bf(v.x * inv) | ((unsigned int)f2bf(v.y * inv) << 16);
    ((unsigned int*)(x0 + (size_t)node * EMBD))[lane] = pack;
}

// per-(dst,rel) counts AND per-dst degree
__global__ void cnt_k(const int* __restrict__ ei, const int* __restrict__ et,
                      unsigned int* __restrict__ cnt, unsigned int* __restrict__ cntd)
{
    int e = blockIdx.x * 256 + threadIdx.x;
    if (e >= NEDGE) return;
    int dst = ei[NEDGE + e];
    atomicAdd(&cnt[(size_t)dst * NREL + et[e]], 1u);
    atomicAdd(&cntd[dst], 1u);
}

// ---- 3-kernel exclusive scan of cntd -> rowptr[NNODES+1] ----
__global__ __launch_bounds__(SCAN_B) void scan1_k(const unsigned int* __restrict__ cntd,
                                                  unsigned int* __restrict__ partial,
                                                  unsigned int* __restrict__ bsum)
{
    __shared__ unsigned int s[SCAN_B];
    int i = blockIdx.x * SCAN_B + threadIdx.x;
    unsigned int v = (i < NNODES) ? cntd[i] : 0u;
    s[threadIdx.x] = v;
    __syncthreads();
    for (int off = 1; off < SCAN_B; off <<= 1) {
        unsigned int t = (threadIdx.x >= off) ? s[threadIdx.x - off] : 0u;
        __syncthreads();
        s[threadIdx.x] += t;
        __syncthreads();
    }
    if (i < NNODES) partial[i] = s[threadIdx.x];          // inclusive within block
    if (threadIdx.x == SCAN_B - 1) bsum[blockIdx.x] = s[SCAN_B - 1];
}

__global__ __launch_bounds__(128) void scan2_k(unsigned int* __restrict__ bsum)
{
    __shared__ unsigned int s[128];
    unsigned int v = (threadIdx.x < SCAN_NB) ? bsum[threadIdx.x] : 0u;
    s[threadIdx.x] = v;
    __syncthreads();
    for (int off = 1; off < 128; off <<= 1) {
        unsigned int t = (threadIdx.x >= off) ? s[threadIdx.x - off] : 0u;
        __syncthreads();
        s[threadIdx.x] += t;
        __syncthreads();
    }
    if (threadIdx.x < SCAN_NB) bsum[threadIdx.x] = s[threadIdx.x];  // inclusive
}

__global__ __launch_bounds__(SCAN_B) void scan3_k(const unsigned int* __restrict__ partial,
                                                  const unsigned int* __restrict__ bsum,
                                                  unsigned int* __restrict__ rowptr)
{
    int i = blockIdx.x * SCAN_B + threadIdx.x;
    if (i >= NNODES) return;
    unsigned int off = (blockIdx.x > 0) ? bsum[blockIdx.x - 1] : 0u;
    rowptr[i + 1] = partial[i] + off;
    if (i == 0) rowptr[0] = 0u;
}

// bucket-fill CSR edge records: (src, type, dinv) grouped by dst
__global__ void fill_k(const int* __restrict__ ei, const int* __restrict__ et,
                       const unsigned int* __restrict__ cnt,
                       const unsigned int* __restrict__ rowptr,
                       unsigned int* __restrict__ cursor,
                       int* __restrict__ esrc, int* __restrict__ etyp,
                       float* __restrict__ edw)
{
    int e = blockIdx.x * 256 + threadIdx.x;
    if (e >= NEDGE) return;
    int dst = ei[NEDGE + e];
    int t = et[e];
    unsigned int c = cnt[(size_t)dst * NREL + t];
    unsigned int pos = rowptr[dst] + atomicAdd(&cursor[dst], 1u);
    esrc[pos] = ei[e];
    etyp[pos] = t;
    edw[pos] = 1.f / (float)(c ? c : 1u);
}

// one wave per dst node: agg[dst] = sum_e (c0*dinv)*h0[src] + (c1*dinv)*h1[src]
__global__ __launch_bounds__(256) void gather_k(
    const unsigned short* __restrict__ h, const float* __restrict__ comp,
    const unsigned int* __restrict__ rowptr,
    const int* __restrict__ esrc, const int* __restrict__ etyp,
    const float* __restrict__ edw, float* __restrict__ agg)
{
    int node = blockIdx.x * 4 + (threadIdx.x >> 6);
    int lane = threadIdx.x & 63;
    unsigned int p0 = rowptr[node], p1 = rowptr[node + 1];
    f4 acc = (f4){0.f, 0.f, 0.f, 0.f};
    for (unsigned int p = p0; p < p1; ++p) {
        int src = esrc[p];
        int t = etyp[p];
        float di = edw[p];
        float w0 = comp[t * 2] * di, w1 = comp[t * 2 + 1] * di;
        const unsigned short* hp = h + (size_t)src * 512 + lane * 4;
        ushort4 u0 = *(const ushort4*)hp;
        ushort4 u1 = *(const ushort4*)(hp + 256);
        acc.x += w0 * bf2f(u0.x) + w1 * bf2f(u1.x);
        acc.y += w0 * bf2f(u0.y) + w1 * bf2f(u1.y);
        acc.z += w0 * bf2f(u0.z) + w1 * bf2f(u1.z);
        acc.w += w0 * bf2f(u0.w) + w1 * bf2f(u1.w);
    }
    *(f4*)(agg + (size_t)node * 256 + lane * 4) = acc;
}

// transpose+convert: in[K,N] f32 -> out[N,K] bf16. grid(ceil(N/256), K)
__global__ void trans_k(const float* __restrict__ in, unsigned short* __restrict__ out,
                        int K, int N)
{
    int n = blockIdx.x * 256 + threadIdx.x;
    int k = blockIdx.y;
    if (n < N) out[(size_t)n * K + k] = f2bf(in[(size_t)k * N + n]);
}

__global__ void bnfin_k(const float* __restrict__ bnsum, const float* __restrict__ gamma,
                        const float* __restrict__ beta, float* __restrict__ bnss)
{
    int c = threadIdx.x;
    float mu = bnsum[c] * (1.f / M_REAL);
    float var = bnsum[256 + c] * (1.f / M_REAL) - mu * mu;
    var = fmaxf(var, 0.f);
    float inv = rsqrtf(var + BN_EPS);
    float sc = gamma[c] * inv;
    bnss[c] = sc;
    bnss[256 + c] = beta[c] - mu * sc;
}

// y(fp32) -> BN scale/shift + relu -> bf16 x_next (or fp32 d_out for last layer)
template<bool LAST>
__global__ __launch_bounds__(256) void apply_k(const float* __restrict__ y,
                                               const float* __restrict__ bnss,
                                               unsigned short* __restrict__ xn,
                                               float* __restrict__ outp)
{
    int i = blockIdx.x * 256 + threadIdx.x;  // 4 elements per thread
    int row = i >> 6;
    int c4 = (i & 63) * 4;
    f4 v = *(const f4*)(y + (size_t)row * 256 + c4);
    f4 sc = *(const f4*)(bnss + c4);
    f4 sh = *(const f4*)(bnss + 256 + c4);
    f4 r;
    r.x = fmaxf(v.x * sc.x + sh.x, 0.f);
    r.y = fmaxf(v.y * sc.y + sh.y, 0.f);
    r.z = fmaxf(v.z * sc.z + sh.z, 0.f);
    r.w = fmaxf(v.w * sc.w + sh.w, 0.f);
    if (LAST) {
        *(f4*)(outp + (size_t)row * 256 + c4) = r;
    } else {
        ushort4 u;
        u.x = f2bf(r.x); u.y = f2bf(r.y); u.z = f2bf(r.z); u.w = f2bf(r.w);
        *(ushort4*)(xn + (size_t)row * 256 + c4) = u;
    }
}

extern "C" void kernel_launch(void* const* d_in, const int* in_sizes, int n_in,
                              void* d_out, int out_size, void* d_ws, size_t ws_size,
                              hipStream_t stream)
{
    const int*   edge_index = (const int*)d_in[0];
    const int*   edge_type  = (const int*)d_in[1];
    const float* emb    = (const float*)d_in[2];
    const float* proj_w = (const float*)d_in[3];
    const float* proj_b = (const float*)d_in[4];
    const float* comp[3]  = {(const float*)d_in[5],  (const float*)d_in[11], (const float*)d_in[17]};
    const float* bases[3] = {(const float*)d_in[6],  (const float*)d_in[12], (const float*)d_in[18]};
    const float* root[3]  = {(const float*)d_in[7],  (const float*)d_in[13], (const float*)d_in[19]};
    const float* biasp[3] = {(const float*)d_in[8],  (const float*)d_in[14], (const float*)d_in[20]};
    const float* gamma[3] = {(const float*)d_in[9],  (const float*)d_in[15], (const float*)d_in[21]};
    const float* beta[3]  = {(const float*)d_in[10], (const float*)d_in[16], (const float*)d_in[22]};

    char* ws = (char*)d_ws;
    size_t off = 0;
    auto alloc = [&](size_t bytes) -> char* {
        char* p = ws + off;
        off = (off + bytes + 255) & ~(size_t)255;
        return p;
    };

    unsigned short* xP  = (unsigned short*)alloc((size_t)M_PAD * 768 * 2);  // proj out; reused as x2
    unsigned short* x1  = (unsigned short*)alloc((size_t)M_PAD * 256 * 2);
    unsigned short* h   = (unsigned short*)alloc((size_t)M_PAD * 512 * 2);  // also y (f32, same bytes)
    float*          agg = (float*)alloc((size_t)M_REAL * 256 * 4);          // x0 aliased inside
    unsigned int*   cnt = (unsigned int*)alloc((size_t)M_REAL * NREL * 4);
    unsigned int*   cntd = (unsigned int*)alloc((size_t)NNODES * 4);
    unsigned int*   rowptr = (unsigned int*)alloc((size_t)(NNODES + 1) * 4);
    unsigned int*   cursor = (unsigned int*)alloc((size_t)NNODES * 4);
    unsigned int*   partial = (unsigned int*)alloc((size_t)NNODES * 4);
    unsigned int*   bsum = (unsigned int*)alloc(128 * 4);
    int*            esrc = (int*)alloc((size_t)NEDGE * 4);
    int*            etyp = (int*)alloc((size_t)NEDGE * 4);
    float*          edw  = (float*)alloc((size_t)NEDGE * 4);
    unsigned short* wTproj = (unsigned short*)alloc((size_t)768 * 128 * 2);
    unsigned short* wTb0 = (unsigned short*)alloc((size_t)512 * 768 * 2);
    unsigned short* wTr0 = (unsigned short*)alloc((size_t)256 * 768 * 2);
    unsigned short* wTb1 = (unsigned short*)alloc((size_t)512 * 256 * 2);
    unsigned short* wTr1 = (unsigned short*)alloc((size_t)256 * 256 * 2);
    unsigned short* wTb2 = (unsigned short*)alloc((size_t)512 * 256 * 2);
    unsigned short* wTr2 = (unsigned short*)alloc((size_t)256 * 256 * 2);
    float* bns  = (float*)alloc(3 * 512 * 4);  // sums (zeroed)
    float* bnss = (float*)alloc(3 * 512 * 4);  // scale/shift

    unsigned short* x0 = (unsigned short*)agg;  // alias: x0 dead before agg written
    unsigned short* x2 = xP;                    // alias: xP dead before x2 written
    float* y = (float*)h;                       // alias: h dead before y written

    hipMemsetAsync(cnt, 0, (size_t)M_REAL * NREL * 4, stream);
    hipMemsetAsync(cntd, 0, (size_t)NNODES * 4, stream);
    hipMemsetAsync(cursor, 0, (size_t)NNODES * 4, stream);
    hipMemsetAsync(bns, 0, 3 * 512 * 4, stream);

    norm_k<<<M_REAL / 4, 256, 0, stream>>>(emb, x0);
    cnt_k<<<(NEDGE + 255) / 256, 256, 0, stream>>>(edge_index, edge_type, cnt, cntd);
    scan1_k<<<SCAN_NB, SCAN_B, 0, stream>>>(cntd, partial, bsum);
    scan2_k<<<1, 128, 0, stream>>>(bsum);
    scan3_k<<<SCAN_NB, SCAN_B, 0, stream>>>(partial, bsum, rowptr);
    fill_k<<<(NEDGE + 255) / 256, 256, 0, stream>>>(edge_index, edge_type, cnt, rowptr,
                                                    cursor, esrc, etyp, edw);

    trans_k<<<dim3(3, 128), 256, 0, stream>>>(proj_w, wTproj, 128, 768);
    trans_k<<<dim3(1, 768), 256, 0, stream>>>(bases[0],           wTb0,            768, 256);
    trans_k<<<dim3(1, 768), 256, 0, stream>>>(bases[0] + 768*256, wTb0 + 256*768,  768, 256);
    trans_k<<<dim3(1, 768), 256, 0, stream>>>(root[0],            wTr0,            768, 256);
    trans_k<<<dim3(1, 256), 256, 0, stream>>>(bases[1],           wTb1,            256, 256);
    trans_k<<<dim3(1, 256), 256, 0, stream>>>(bases[1] + 256*256, wTb1 + 256*256,  256, 256);
    trans_k<<<dim3(1, 256), 256, 0, stream>>>(root[1],            wTr1,            256, 256);
    trans_k<<<dim3(1, 256), 256, 0, stream>>>(bases[2],           wTb2,            256, 256);
    trans_k<<<dim3(1, 256), 256, 0, stream>>>(bases[2] + 256*256, wTb2 + 256*256,  256, 256);
    trans_k<<<dim3(1, 256), 256, 0, stream>>>(root[2],            wTr2,            256, 256);

    // projection: [50000,128] @ [128,768] + b
    gemm_k<128, 768, true, false><<<dim3(6, M_TILES), 256, 0, stream>>>(
        x0, wTproj, proj_b, nullptr, nullptr, xP);

    // ---- layer 0 (d_in = 768) ----
    gemm_k<768, 512, false, false><<<dim3(4, M_TILES), 256, 0, stream>>>(
        xP, wTb0, nullptr, nullptr, nullptr, h);
    gather_k<<<NNODES / 4, 256, 0, stream>>>(h, comp[0], rowptr, esrc, etyp, edw, agg);
    gemm_k<768, 256, true, true><<<dim3(2, M_TILES), 256, 0, stream>>>(
        xP, wTr0, biasp[0], agg, bns + 0 * 512, y);
    bnfin_k<<<1, 256, 0, stream>>>(bns + 0 * 512, gamma[0], beta[0], bnss + 0 * 512);
    apply_k<false><<<(M_REAL * 64) / 256, 256, 0, stream>>>(y, bnss + 0 * 512, x1, nullptr);

    // ---- layer 1 (d_in = 256) ----
    gemm_k<256, 512, false, false><<<dim3(4, M_TILES), 256, 0, stream>>>(
        x1, wTb1, nullptr, nullptr, nullptr, h);
    gather_k<<<NNODES / 4, 256, 0, stream>>>(h, comp[1], rowptr, esrc, etyp, edw, agg);
    gemm_k<256, 256, true, true><<<dim3(2, M_TILES), 256, 0, stream>>>(
        x1, wTr1, biasp[1], agg, bns + 1 * 512, y);
    bnfin_k<<<1, 256, 0, stream>>>(bns + 1 * 512, gamma[1], beta[1], bnss + 1 * 512);
    apply_k<false><<<(M_REAL * 64) / 256, 256, 0, stream>>>(y, bnss + 1 * 512, x2, nullptr);

    // ---- layer 2 (d_in = 256) ----
    gemm_k<256, 512, false, false><<<dim3(4, M_TILES), 256, 0, stream>>>(
        x2, wTb2, nullptr, nullptr, nullptr, h);
    gather_k<<<NNODES / 4, 256, 0, stream>>>(h, comp[2], rowptr, esrc, etyp, edw, agg);
    gemm_k<256, 256, true, true><<<dim3(2, M_TILES), 256, 0, stream>>>(
        x2, wTr2, biasp[2], agg, bns + 2 * 512, y);
    bnfin_k<<<1, 256, 0, stream>>>(bns + 2 * 512, gamma[2], beta[2], bnss + 2 * 512);
    apply_k<true><<<(M_REAL * 64) / 256, 256, 0, stream>>>(y, bnss + 2 * 512, nullptr, (float*)d_out);
}

// Round 4
// 762.689 us; speedup vs baseline: 6.2731x; 1.3604x over previous
//
#include <hip/hip_runtime.h>
#include <hip/hip_bf16.h>

#define NNODES 50000
#define EMBD   128
#define PROJD  768
#define HID    256
#define NREL   16
#define NEDGE  400000
#define BN_EPS 1e-5f
#define M_REAL NNODES
#define M_TILES 391            /* ceil(50000/128) */
#define M_PAD  (M_TILES*128)   /* 50048 */
#define RPX    49              /* ceil(391/8) row-blocks per XCD */
#define SCAN_B 512
#define SCAN_NB ((NNODES + SCAN_B - 1) / SCAN_B)   /* 98 */

typedef __attribute__((ext_vector_type(8))) short short8;
typedef __attribute__((ext_vector_type(4))) float f4;

__device__ __forceinline__ float bf2f(unsigned short u) {
    union { unsigned int i; float f; } x; x.i = ((unsigned int)u) << 16; return x.f;
}
__device__ __forceinline__ unsigned short f2bf(float f) {
    __hip_bfloat16 h = __float2bfloat16(f);
    union { __hip_bfloat16 h; unsigned short u; } x; x.h = h; return x.u;
}

// async global->LDS, 16B per lane; LDS dest = wave-uniform base + lane*16
__device__ __forceinline__ void g2l16(const unsigned short* g, unsigned short* l) {
    __builtin_amdgcn_global_load_lds(
        (const __attribute__((address_space(1))) unsigned int*)g,
        (__attribute__((address_space(3))) unsigned int*)l,
        16, 0, 0);
}

// ---------------------------------------------------------------------------
// GEMM: C[M,N] = A[M,K](bf16) @ W^T[N,K](bf16)   (+bias) (+agg, fp32 out, BN sums)
// m97 structure: 128x128 tile, BK=64, global_load_lds(16B) staging, 2-barrier
// K-loop, ds_read_b128 fragments, 4 waves x (4x4) 16x16x32 MFMAs.
// LDS chunk swizzle: logical 16B-chunk c of tile-row r sits at physical
// chunk (c + r) % 8 — expressed via the per-lane GLOBAL source address
// (HW pins lane l -> LDS base + l*16). Spreads frag ds_reads over all 32 banks.
// XCD swizzle: bid&7 picks XCD; each XCD owns a contiguous row range with
// n-tile fastest -> A rows L2-resident across their NT blocks.
// ---------------------------------------------------------------------------
template<int K, int N, bool BIAS, bool ROOT>
__global__ __launch_bounds__(256) void gemm_k(
    const unsigned short* __restrict__ A,
    const unsigned short* __restrict__ WT,
    const float* __restrict__ bias,
    const float* __restrict__ agg,
    float* __restrict__ bnsum,
    void* __restrict__ outv)
{
    static_assert(!ROOT || N == 256, "ROOT mode assumes N==256");
    constexpr int NT = N / 128;
    const int lin = blockIdx.x;
    const int xcd = lin & 7;
    const int idx = lin >> 3;
    const int row_blk = xcd * RPX + idx / NT;
    const int nt = idx % NT;
    if (row_blk >= M_TILES) return;
    const int tile_m = row_blk * 128;
    const int tile_n = nt * 128;

    __shared__ unsigned short As[128 * 64];
    __shared__ unsigned short Bs[128 * 64];

    const int w = threadIdx.x >> 6;
    const int l = threadIdx.x & 63;
    const int lm = l & 15;
    const int kq = l >> 4;
    const int wm = (w & 1) << 6;
    const int wn = (w >> 1) << 6;

    // ---- staging setup (per-thread, K-loop invariant) ----
    const int lrow = l >> 3;                       // row-within-8 handled by this lane
    const int chunk = ((l & 7) + 8 - lrow) & 7;    // swizzled source chunk
    const unsigned short* srcA[4];
    const unsigned short* srcB[4];
    unsigned short* dstA[4];
    unsigned short* dstB[4];
#pragma unroll
    for (int it = 0; it < 4; ++it) {
        int rt = it * 32 + w * 8 + lrow;           // tile row 0..127
        int rg = tile_m + rt; if (rg >= M_REAL) rg = M_REAL - 1;
        srcA[it] = A  + (size_t)rg * K + chunk * 8;
        srcB[it] = WT + (size_t)(tile_n + rt) * K + chunk * 8;
        dstA[it] = As + (it * 32 + w * 8) * 64;    // wave-uniform LDS base
        dstB[it] = Bs + (it * 32 + w * 8) * 64;
    }

    // ---- fragment LDS byte-offsets (K-loop invariant; kh=1 is ^64) ----
    unsigned aoff[4], boff[4];
#pragma unroll
    for (int mi = 0; mi < 4; ++mi) {
        aoff[mi] = (unsigned)((wm + mi * 16 + lm) * 128 + (((kq + lm) & 7) << 4));
        boff[mi] = (unsigned)((wn + mi * 16 + lm) * 128 + (((kq + lm) & 7) << 4));
    }

    f4 acc[4][4];
#pragma unroll
    for (int mi = 0; mi < 4; ++mi)
#pragma unroll
        for (int ni = 0; ni < 4; ++ni) acc[mi][ni] = (f4){0.f, 0.f, 0.f, 0.f};

    for (int kc = 0; kc < K; kc += 64) {
#pragma unroll
        for (int it = 0; it < 4; ++it) {
            g2l16(srcA[it] + kc, dstA[it]);
            g2l16(srcB[it] + kc, dstB[it]);
        }
        __syncthreads();   // drains vmcnt (compiler emits full waitcnt before s_barrier)
#pragma unroll
        for (int kh = 0; kh < 2; ++kh) {
            const unsigned x = kh << 6;
            short8 af[4], bfr[4];
#pragma unroll
            for (int mi = 0; mi < 4; ++mi)
                af[mi] = *(const short8*)((const char*)As + (aoff[mi] ^ x));
#pragma unroll
            for (int ni = 0; ni < 4; ++ni)
                bfr[ni] = *(const short8*)((const char*)Bs + (boff[ni] ^ x));
#pragma unroll
            for (int mi = 0; mi < 4; ++mi)
#pragma unroll
                for (int ni = 0; ni < 4; ++ni)
                    acc[mi][ni] = __builtin_amdgcn_mfma_f32_16x16x32_bf16(
                        af[mi], bfr[ni], acc[mi][ni], 0, 0, 0);
        }
        __syncthreads();   // protect LDS before next staging
    }

    int cols[4]; float bv[4];
#pragma unroll
    for (int ni = 0; ni < 4; ++ni) {
        cols[ni] = tile_n + wn + ni * 16 + lm;
        bv[ni] = BIAS ? bias[cols[ni]] : 0.f;
    }

    if (!ROOT) {
        unsigned short* O = (unsigned short*)outv;
#pragma unroll
        for (int mi = 0; mi < 4; ++mi) {
#pragma unroll
            for (int rg = 0; rg < 4; ++rg) {
                int row = tile_m + wm + mi * 16 + kq * 4 + rg;
                if (row < M_REAL) {
                    size_t base = (size_t)row * N;
#pragma unroll
                    for (int ni = 0; ni < 4; ++ni)
                        O[base + cols[ni]] = f2bf(acc[mi][ni][rg] + bv[ni]);
                }
            }
        }
    } else {
        float* O = (float*)outv;
        float s1[4] = {0.f, 0.f, 0.f, 0.f}, s2[4] = {0.f, 0.f, 0.f, 0.f};
#pragma unroll
        for (int mi = 0; mi < 4; ++mi) {
#pragma unroll
            for (int rg = 0; rg < 4; ++rg) {
                int row = tile_m + wm + mi * 16 + kq * 4 + rg;
                if (row < M_REAL) {
                    size_t base = (size_t)row * 256;
#pragma unroll
                    for (int ni = 0; ni < 4; ++ni) {
                        float v = acc[mi][ni][rg] + bv[ni] + agg[base + cols[ni]];
                        O[base + cols[ni]] = v;
                        s1[ni] += v; s2[ni] += v * v;
                    }
                }
            }
        }
#pragma unroll
        for (int ni = 0; ni < 4; ++ni) {
            float a = s1[ni], b = s2[ni];
            a += __shfl_xor(a, 16); a += __shfl_xor(a, 32);
            b += __shfl_xor(b, 16); b += __shfl_xor(b, 32);
            if (l < 16) {
                atomicAdd(&bnsum[cols[ni]], a);
                atomicAdd(&bnsum[256 + cols[ni]], b);
            }
        }
    }
}

// row L2-normalize emb -> bf16 x0. One wave per node (128 cols = 2/lane).
__global__ __launch_bounds__(256) void norm_k(const float* __restrict__ emb,
                                              unsigned short* __restrict__ x0)
{
    int node = blockIdx.x * 4 + (threadIdx.x >> 6);
    int lane = threadIdx.x & 63;
    const float2* p = (const float2*)(emb + (size_t)node * EMBD);
    float2 v = p[lane];
    float ss = v.x * v.x + v.y * v.y;
#pragma unroll
    for (int o = 32; o > 0; o >>= 1) ss += __shfl_xor(ss, o);
    float inv = 1.f / fmaxf(sqrtf(ss), 1e-12f);
    unsigned int pack = (unsigned int)f2bf(v.x * inv) | ((unsigned int)f2bf(v.y * inv) << 16);
    ((unsigned int*)(x0 + (size_t)node * EMBD))[lane] = pack;
}

// per-(dst,rel) counts AND per-dst degree
__global__ void cnt_k(const int* __restrict__ ei, const int* __restrict__ et,
                      unsigned int* __restrict__ cnt, unsigned int* __restrict__ cntd)
{
    int e = blockIdx.x * 256 + threadIdx.x;
    if (e >= NEDGE) return;
    int dst = ei[NEDGE + e];
    atomicAdd(&cnt[(size_t)dst * NREL + et[e]], 1u);
    atomicAdd(&cntd[dst], 1u);
}

// ---- 3-kernel exclusive scan of cntd -> rowptr[NNODES+1] ----
__global__ __launch_bounds__(SCAN_B) void scan1_k(const unsigned int* __restrict__ cntd,
                                                  unsigned int* __restrict__ partial,
                                                  unsigned int* __restrict__ bsum)
{
    __shared__ unsigned int s[SCAN_B];
    int i = blockIdx.x * SCAN_B + threadIdx.x;
    unsigned int v = (i < NNODES) ? cntd[i] : 0u;
    s[threadIdx.x] = v;
    __syncthreads();
    for (int off = 1; off < SCAN_B; off <<= 1) {
        unsigned int t = (threadIdx.x >= off) ? s[threadIdx.x - off] : 0u;
        __syncthreads();
        s[threadIdx.x] += t;
        __syncthreads();
    }
    if (i < NNODES) partial[i] = s[threadIdx.x];          // inclusive within block
    if (threadIdx.x == SCAN_B - 1) bsum[blockIdx.x] = s[SCAN_B - 1];
}

__global__ __launch_bounds__(128) void scan2_k(unsigned int* __restrict__ bsum)
{
    __shared__ unsigned int s[128];
    unsigned int v = (threadIdx.x < SCAN_NB) ? bsum[threadIdx.x] : 0u;
    s[threadIdx.x] = v;
    __syncthreads();
    for (int off = 1; off < 128; off <<= 1) {
        unsigned int t = (threadIdx.x >= off) ? s[threadIdx.x - off] : 0u;
        __syncthreads();
        s[threadIdx.x] += t;
        __syncthreads();
    }
    if (threadIdx.x < SCAN_NB) bsum[threadIdx.x] = s[threadIdx.x];  // inclusive
}

__global__ __launch_bounds__(SCAN_B) void scan3_k(const unsigned int* __restrict__ partial,
                                                  const unsigned int* __restrict__ bsum,
                                                  unsigned int* __restrict__ rowptr)
{
    int i = blockIdx.x * SCAN_B + threadIdx.x;
    if (i >= NNODES) return;
    unsigned int off = (blockIdx.x > 0) ? bsum[blockIdx.x - 1] : 0u;
    rowptr[i + 1] = partial[i] + off;
    if (i == 0) rowptr[0] = 0u;
}

// bucket-fill CSR edge records: (src, type, dinv) grouped by dst
__global__ void fill_k(const int* __restrict__ ei, const int* __restrict__ et,
                       const unsigned int* __restrict__ cnt,
                       const unsigned int* __restrict__ rowptr,
                       unsigned int* __restrict__ cursor,
                       int* __restrict__ esrc, int* __restrict__ etyp,
                       float* __restrict__ edw)
{
    int e = blockIdx.x * 256 + threadIdx.x;
    if (e >= NEDGE) return;
    int dst = ei[NEDGE + e];
    int t = et[e];
    unsigned int c = cnt[(size_t)dst * NREL + t];
    unsigned int pos = rowptr[dst] + atomicAdd(&cursor[dst], 1u);
    esrc[pos] = ei[e];
    etyp[pos] = t;
    edw[pos] = 1.f / (float)(c ? c : 1u);
}

// one wave per dst node: agg[dst] = sum_e (c0*dinv)*h0[src] + (c1*dinv)*h1[src]
__global__ __launch_bounds__(256) void gather_k(
    const unsigned short* __restrict__ h, const float* __restrict__ comp,
    const unsigned int* __restrict__ rowptr,
    const int* __restrict__ esrc, const int* __restrict__ etyp,
    const float* __restrict__ edw, float* __restrict__ agg)
{
    int node = blockIdx.x * 4 + (threadIdx.x >> 6);
    int lane = threadIdx.x & 63;
    unsigned int p0 = rowptr[node], p1 = rowptr[node + 1];
    f4 acc = (f4){0.f, 0.f, 0.f, 0.f};
    for (unsigned int p = p0; p < p1; ++p) {
        int src = esrc[p];
        int t = etyp[p];
        float di = edw[p];
        float w0 = comp[t * 2] * di, w1 = comp[t * 2 + 1] * di;
        const unsigned short* hp = h + (size_t)src * 512 + lane * 4;
        ushort4 u0 = *(const ushort4*)hp;
        ushort4 u1 = *(const ushort4*)(hp + 256);
        acc.x += w0 * bf2f(u0.x) + w1 * bf2f(u1.x);
        acc.y += w0 * bf2f(u0.y) + w1 * bf2f(u1.y);
        acc.z += w0 * bf2f(u0.z) + w1 * bf2f(u1.z);
        acc.w += w0 * bf2f(u0.w) + w1 * bf2f(u1.w);
    }
    *(f4*)(agg + (size_t)node * 256 + lane * 4) = acc;
}

// transpose+convert: in[K,N] f32 -> out[N,K] bf16. grid(ceil(N/256), K)
__global__ void trans_k(const float* __restrict__ in, unsigned short* __restrict__ out,
                        int K, int N)
{
    int n = blockIdx.x * 256 + threadIdx.x;
    int k = blockIdx.y;
    if (n < N) out[(size_t)n * K + k] = f2bf(in[(size_t)k * N + n]);
}

__global__ void bnfin_k(const float* __restrict__ bnsum, const float* __restrict__ gamma,
                        const float* __restrict__ beta, float* __restrict__ bnss)
{
    int c = threadIdx.x;
    float mu = bnsum[c] * (1.f / M_REAL);
    float var = bnsum[256 + c] * (1.f / M_REAL) - mu * mu;
    var = fmaxf(var, 0.f);
    float inv = rsqrtf(var + BN_EPS);
    float sc = gamma[c] * inv;
    bnss[c] = sc;
    bnss[256 + c] = beta[c] - mu * sc;
}

// y(fp32) -> BN scale/shift + relu -> bf16 x_next (or fp32 d_out for last layer)
template<bool LAST>
__global__ __launch_bounds__(256) void apply_k(const float* __restrict__ y,
                                               const float* __restrict__ bnss,
                                               unsigned short* __restrict__ xn,
                                               float* __restrict__ outp)
{
    int i = blockIdx.x * 256 + threadIdx.x;  // 4 elements per thread
    int row = i >> 6;
    int c4 = (i & 63) * 4;
    f4 v = *(const f4*)(y + (size_t)row * 256 + c4);
    f4 sc = *(const f4*)(bnss + c4);
    f4 sh = *(const f4*)(bnss + 256 + c4);
    f4 r;
    r.x = fmaxf(v.x * sc.x + sh.x, 0.f);
    r.y = fmaxf(v.y * sc.y + sh.y, 0.f);
    r.z = fmaxf(v.z * sc.z + sh.z, 0.f);
    r.w = fmaxf(v.w * sc.w + sh.w, 0.f);
    if (LAST) {
        *(f4*)(outp + (size_t)row * 256 + c4) = r;
    } else {
        ushort4 u;
        u.x = f2bf(r.x); u.y = f2bf(r.y); u.z = f2bf(r.z); u.w = f2bf(r.w);
        *(ushort4*)(xn + (size_t)row * 256 + c4) = u;
    }
}

extern "C" void kernel_launch(void* const* d_in, const int* in_sizes, int n_in,
                              void* d_out, int out_size, void* d_ws, size_t ws_size,
                              hipStream_t stream)
{
    const int*   edge_index = (const int*)d_in[0];
    const int*   edge_type  = (const int*)d_in[1];
    const float* emb    = (const float*)d_in[2];
    const float* proj_w = (const float*)d_in[3];
    const float* proj_b = (const float*)d_in[4];
    const float* comp[3]  = {(const float*)d_in[5],  (const float*)d_in[11], (const float*)d_in[17]};
    const float* bases[3] = {(const float*)d_in[6],  (const float*)d_in[12], (const float*)d_in[18]};
    const float* root[3]  = {(const float*)d_in[7],  (const float*)d_in[13], (const float*)d_in[19]};
    const float* biasp[3] = {(const float*)d_in[8],  (const float*)d_in[14], (const float*)d_in[20]};
    const float* gamma[3] = {(const float*)d_in[9],  (const float*)d_in[15], (const float*)d_in[21]};
    const float* beta[3]  = {(const float*)d_in[10], (const float*)d_in[16], (const float*)d_in[22]};

    char* ws = (char*)d_ws;
    size_t off = 0;
    auto alloc = [&](size_t bytes) -> char* {
        char* p = ws + off;
        off = (off + bytes + 255) & ~(size_t)255;
        return p;
    };

    unsigned short* xP  = (unsigned short*)alloc((size_t)M_PAD * 768 * 2);  // proj out; reused as x2
    unsigned short* x1  = (unsigned short*)alloc((size_t)M_PAD * 256 * 2);
    unsigned short* h   = (unsigned short*)alloc((size_t)M_PAD * 512 * 2);  // also y (f32, same bytes)
    float*          agg = (float*)alloc((size_t)M_REAL * 256 * 4);          // x0 aliased inside
    unsigned int*   cnt = (unsigned int*)alloc((size_t)M_REAL * NREL * 4);
    unsigned int*   cntd = (unsigned int*)alloc((size_t)NNODES * 4);
    unsigned int*   rowptr = (unsigned int*)alloc((size_t)(NNODES + 1) * 4);
    unsigned int*   cursor = (unsigned int*)alloc((size_t)NNODES * 4);
    unsigned int*   partial = (unsigned int*)alloc((size_t)NNODES * 4);
    unsigned int*   bsum = (unsigned int*)alloc(128 * 4);
    int*            esrc = (int*)alloc((size_t)NEDGE * 4);
    int*            etyp = (int*)alloc((size_t)NEDGE * 4);
    float*          edw  = (float*)alloc((size_t)NEDGE * 4);
    unsigned short* wTproj = (unsigned short*)alloc((size_t)768 * 128 * 2);
    unsigned short* wTb0 = (unsigned short*)alloc((size_t)512 * 768 * 2);
    unsigned short* wTr0 = (unsigned short*)alloc((size_t)256 * 768 * 2);
    unsigned short* wTb1 = (unsigned short*)alloc((size_t)512 * 256 * 2);
    unsigned short* wTr1 = (unsigned short*)alloc((size_t)256 * 256 * 2);
    unsigned short* wTb2 = (unsigned short*)alloc((size_t)512 * 256 * 2);
    unsigned short* wTr2 = (unsigned short*)alloc((size_t)256 * 256 * 2);
    float* bns  = (float*)alloc(3 * 512 * 4);  // sums (zeroed)
    float* bnss = (float*)alloc(3 * 512 * 4);  // scale/shift

    unsigned short* x0 = (unsigned short*)agg;  // alias: x0 dead before agg written
    unsigned short* x2 = xP;                    // alias: xP dead before x2 written
    float* y = (float*)h;                       // alias: h dead before y written

    hipMemsetAsync(cnt, 0, (size_t)M_REAL * NREL * 4, stream);
    hipMemsetAsync(cntd, 0, (size_t)NNODES * 4, stream);
    hipMemsetAsync(cursor, 0, (size_t)NNODES * 4, stream);
    hipMemsetAsync(bns, 0, 3 * 512 * 4, stream);

    norm_k<<<M_REAL / 4, 256, 0, stream>>>(emb, x0);
    cnt_k<<<(NEDGE + 255) / 256, 256, 0, stream>>>(edge_index, edge_type, cnt, cntd);
    scan1_k<<<SCAN_NB, SCAN_B, 0, stream>>>(cntd, partial, bsum);
    scan2_k<<<1, 128, 0, stream>>>(bsum);
    scan3_k<<<SCAN_NB, SCAN_B, 0, stream>>>(partial, bsum, rowptr);
    fill_k<<<(NEDGE + 255) / 256, 256, 0, stream>>>(edge_index, edge_type, cnt, rowptr,
                                                    cursor, esrc, etyp, edw);

    trans_k<<<dim3(3, 128), 256, 0, stream>>>(proj_w, wTproj, 128, 768);
    trans_k<<<dim3(1, 768), 256, 0, stream>>>(bases[0],           wTb0,            768, 256);
    trans_k<<<dim3(1, 768), 256, 0, stream>>>(bases[0] + 768*256, wTb0 + 256*768,  768, 256);
    trans_k<<<dim3(1, 768), 256, 0, stream>>>(root[0],            wTr0,            768, 256);
    trans_k<<<dim3(1, 256), 256, 0, stream>>>(bases[1],           wTb1,            256, 256);
    trans_k<<<dim3(1, 256), 256, 0, stream>>>(bases[1] + 256*256, wTb1 + 256*256,  256, 256);
    trans_k<<<dim3(1, 256), 256, 0, stream>>>(root[1],            wTr1,            256, 256);
    trans_k<<<dim3(1, 256), 256, 0, stream>>>(bases[2],           wTb2,            256, 256);
    trans_k<<<dim3(1, 256), 256, 0, stream>>>(bases[2] + 256*256, wTb2 + 256*256,  256, 256);
    trans_k<<<dim3(1, 256), 256, 0, stream>>>(root[2],            wTr2,            256, 256);

    // projection: [50000,128] @ [128,768] + b
    gemm_k<128, 768, true, false><<<8 * RPX * 6, 256, 0, stream>>>(
        x0, wTproj, proj_b, nullptr, nullptr, xP);

    // ---- layer 0 (d_in = 768) ----
    gemm_k<768, 512, false, false><<<8 * RPX * 4, 256, 0, stream>>>(
        xP, wTb0, nullptr, nullptr, nullptr, h);
    gather_k<<<NNODES / 4, 256, 0, stream>>>(h, comp[0], rowptr, esrc, etyp, edw, agg);
    gemm_k<768, 256, true, true><<<8 * RPX * 2, 256, 0, stream>>>(
        xP, wTr0, biasp[0], agg, bns + 0 * 512, y);
    bnfin_k<<<1, 256, 0, stream>>>(bns + 0 * 512, gamma[0], beta[0], bnss + 0 * 512);
    apply_k<false><<<(M_REAL * 64) / 256, 256, 0, stream>>>(y, bnss + 0 * 512, x1, nullptr);

    // ---- layer 1 (d_in = 256) ----
    gemm_k<256, 512, false, false><<<8 * RPX * 4, 256, 0, stream>>>(
        x1, wTb1, nullptr, nullptr, nullptr, h);
    gather_k<<<NNODES / 4, 256, 0, stream>>>(h, comp[1], rowptr, esrc, etyp, edw, agg);
    gemm_k<256, 256, true, true><<<8 * RPX * 2, 256, 0, stream>>>(
        x1, wTr1, biasp[1], agg, bns + 1 * 512, y);
    bnfin_k<<<1, 256, 0, stream>>>(bns + 1 * 512, gamma[1], beta[1], bnss + 1 * 512);
    apply_k<false><<<(M_REAL * 64) / 256, 256, 0, stream>>>(y, bnss + 1 * 512, x2, nullptr);

    // ---- layer 2 (d_in = 256) ----
    gemm_k<256, 512, false, false><<<8 * RPX * 4, 256, 0, stream>>>(
        x2, wTb2, nullptr, nullptr, nullptr, h);
    gather_k<<<NNODES / 4, 256, 0, stream>>>(h, comp[2], rowptr, esrc, etyp, edw, agg);
    gemm_k<256, 256, true, true><<<8 * RPX * 2, 256, 0, stream>>>(
        x2, wTr2, biasp[2], agg, bns + 2 * 512, y);
    bnfin_k<<<1, 256, 0, stream>>>(bns + 2 * 512, gamma[2], beta[2], bnss + 2 * 512);
    apply_k<true><<<(M_REAL * 64) / 256, 256, 0, stream>>>(y, bnss + 2 * 512, nullptr, (float*)d_out);
}

// Round 5
// 717.057 us; speedup vs baseline: 6.6723x; 1.0636x over previous
//
#include <hip/hip_runtime.h>
#include <hip/hip_bf16.h>

#define NNODES 50000
#define EMBD   128
#define PROJD  768
#define HID    256
#define NREL   16
#define NEDGE  400000
#define BN_EPS 1e-5f
#define M_REAL NNODES
#define M_TILES 391            /* ceil(50000/128) */
#define M_PAD  (M_TILES*128)   /* 50048 */
#define RPX    49              /* ceil(391/8) row-blocks per XCD */
#define SCAN_B 512
#define SCAN_NB ((NNODES + SCAN_B - 1) / SCAN_B)   /* 98 */

typedef __attribute__((ext_vector_type(8))) short short8;
typedef __attribute__((ext_vector_type(4))) float f4;

__device__ __forceinline__ float bf2f(unsigned short u) {
    union { unsigned int i; float f; } x; x.i = ((unsigned int)u) << 16; return x.f;
}
__device__ __forceinline__ unsigned short f2bf(float f) {
    __hip_bfloat16 h = __float2bfloat16(f);
    union { __hip_bfloat16 h; unsigned short u; } x; x.h = h; return x.u;
}

// async global->LDS, 16B per lane; LDS dest = wave-uniform base + lane*16
__device__ __forceinline__ void g2l16(const unsigned short* g, unsigned short* l) {
    __builtin_amdgcn_global_load_lds(
        (const __attribute__((address_space(1))) unsigned int*)g,
        (__attribute__((address_space(3))) unsigned int*)l,
        16, 0, 0);
}

// ---------------------------------------------------------------------------
// GEMM: C[M,N] = A[M,K](bf16) @ W^T[N,K](bf16)   (+bias) (+agg, fp32 out, BN sums)
// m97 structure: 128x128 tile, BK=64, global_load_lds(16B) staging, 2-barrier
// K-loop, ds_read_b128 fragments, 4 waves x (4x4) 16x16x32 MFMAs.
// LDS chunk swizzle via the per-lane GLOBAL source address; XCD-aware block
// swizzle (bid&7) for A-row L2 residency.
// ---------------------------------------------------------------------------
template<int K, int N, bool BIAS, bool ROOT>
__global__ __launch_bounds__(256) void gemm_k(
    const unsigned short* __restrict__ A,
    const unsigned short* __restrict__ WT,
    const float* __restrict__ bias,
    const float* __restrict__ agg,
    float* __restrict__ bnsum,
    void* __restrict__ outv)
{
    static_assert(!ROOT || N == 256, "ROOT mode assumes N==256");
    constexpr int NT = N / 128;
    const int lin = blockIdx.x;
    const int xcd = lin & 7;
    const int idx = lin >> 3;
    const int row_blk = xcd * RPX + idx / NT;
    const int nt = idx % NT;
    if (row_blk >= M_TILES) return;
    const int tile_m = row_blk * 128;
    const int tile_n = nt * 128;

    __shared__ unsigned short As[128 * 64];
    __shared__ unsigned short Bs[128 * 64];

    const int w = threadIdx.x >> 6;
    const int l = threadIdx.x & 63;
    const int lm = l & 15;
    const int kq = l >> 4;
    const int wm = (w & 1) << 6;
    const int wn = (w >> 1) << 6;

    // ---- staging setup (per-thread, K-loop invariant) ----
    const int lrow = l >> 3;                       // row-within-8 handled by this lane
    const int chunk = ((l & 7) + 8 - lrow) & 7;    // swizzled source chunk
    const unsigned short* srcA[4];
    const unsigned short* srcB[4];
    unsigned short* dstA[4];
    unsigned short* dstB[4];
#pragma unroll
    for (int it = 0; it < 4; ++it) {
        int rt = it * 32 + w * 8 + lrow;           // tile row 0..127
        int rg = tile_m + rt; if (rg >= M_REAL) rg = M_REAL - 1;
        srcA[it] = A  + (size_t)rg * K + chunk * 8;
        srcB[it] = WT + (size_t)(tile_n + rt) * K + chunk * 8;
        dstA[it] = As + (it * 32 + w * 8) * 64;    // wave-uniform LDS base
        dstB[it] = Bs + (it * 32 + w * 8) * 64;
    }

    // ---- fragment LDS byte-offsets (K-loop invariant; kh=1 is ^64) ----
    unsigned aoff[4], boff[4];
#pragma unroll
    for (int mi = 0; mi < 4; ++mi) {
        aoff[mi] = (unsigned)((wm + mi * 16 + lm) * 128 + (((kq + lm) & 7) << 4));
        boff[mi] = (unsigned)((wn + mi * 16 + lm) * 128 + (((kq + lm) & 7) << 4));
    }

    f4 acc[4][4];
#pragma unroll
    for (int mi = 0; mi < 4; ++mi)
#pragma unroll
        for (int ni = 0; ni < 4; ++ni) acc[mi][ni] = (f4){0.f, 0.f, 0.f, 0.f};

    for (int kc = 0; kc < K; kc += 64) {
#pragma unroll
        for (int it = 0; it < 4; ++it) {
            g2l16(srcA[it] + kc, dstA[it]);
            g2l16(srcB[it] + kc, dstB[it]);
        }
        __syncthreads();
#pragma unroll
        for (int kh = 0; kh < 2; ++kh) {
            const unsigned x = kh << 6;
            short8 af[4], bfr[4];
#pragma unroll
            for (int mi = 0; mi < 4; ++mi)
                af[mi] = *(const short8*)((const char*)As + (aoff[mi] ^ x));
#pragma unroll
            for (int ni = 0; ni < 4; ++ni)
                bfr[ni] = *(const short8*)((const char*)Bs + (boff[ni] ^ x));
#pragma unroll
            for (int mi = 0; mi < 4; ++mi)
#pragma unroll
                for (int ni = 0; ni < 4; ++ni)
                    acc[mi][ni] = __builtin_amdgcn_mfma_f32_16x16x32_bf16(
                        af[mi], bfr[ni], acc[mi][ni], 0, 0, 0);
        }
        __syncthreads();
    }

    int cols[4]; float bv[4];
#pragma unroll
    for (int ni = 0; ni < 4; ++ni) {
        cols[ni] = tile_n + wn + ni * 16 + lm;
        bv[ni] = BIAS ? bias[cols[ni]] : 0.f;
    }

    if (!ROOT) {
        unsigned short* O = (unsigned short*)outv;
#pragma unroll
        for (int mi = 0; mi < 4; ++mi) {
#pragma unroll
            for (int rg = 0; rg < 4; ++rg) {
                int row = tile_m + wm + mi * 16 + kq * 4 + rg;
                if (row < M_REAL) {
                    size_t base = (size_t)row * N;
#pragma unroll
                    for (int ni = 0; ni < 4; ++ni)
                        O[base + cols[ni]] = f2bf(acc[mi][ni][rg] + bv[ni]);
                }
            }
        }
    } else {
        float* O = (float*)outv;
        float s1[4] = {0.f, 0.f, 0.f, 0.f}, s2[4] = {0.f, 0.f, 0.f, 0.f};
#pragma unroll
        for (int mi = 0; mi < 4; ++mi) {
#pragma unroll
            for (int rg = 0; rg < 4; ++rg) {
                int row = tile_m + wm + mi * 16 + kq * 4 + rg;
                if (row < M_REAL) {
                    size_t base = (size_t)row * 256;
#pragma unroll
                    for (int ni = 0; ni < 4; ++ni) {
                        float v = acc[mi][ni][rg] + bv[ni] + agg[base + cols[ni]];
                        O[base + cols[ni]] = v;
                        s1[ni] += v; s2[ni] += v * v;
                    }
                }
            }
        }
#pragma unroll
        for (int ni = 0; ni < 4; ++ni) {
            float a = s1[ni], b = s2[ni];
            a += __shfl_xor(a, 16); a += __shfl_xor(a, 32);
            b += __shfl_xor(b, 16); b += __shfl_xor(b, 32);
            if (l < 16) {
                atomicAdd(&bnsum[cols[ni]], a);
                atomicAdd(&bnsum[256 + cols[ni]], b);
            }
        }
    }
}

// row L2-normalize emb -> bf16 x0. One wave per node (128 cols = 2/lane).
__global__ __launch_bounds__(256) void norm_k(const float* __restrict__ emb,
                                              unsigned short* __restrict__ x0)
{
    int node = blockIdx.x * 4 + (threadIdx.x >> 6);
    int lane = threadIdx.x & 63;
    const float2* p = (const float2*)(emb + (size_t)node * EMBD);
    float2 v = p[lane];
    float ss = v.x * v.x + v.y * v.y;
#pragma unroll
    for (int o = 32; o > 0; o >>= 1) ss += __shfl_xor(ss, o);
    float inv = 1.f / fmaxf(sqrtf(ss), 1e-12f);
    unsigned int pack = (unsigned int)f2bf(v.x * inv) | ((unsigned int)f2bf(v.y * inv) << 16);
    ((unsigned int*)(x0 + (size_t)node * EMBD))[lane] = pack;
}

// per-(dst,rel) counts AND per-dst degree
__global__ void cnt_k(const int* __restrict__ ei, const int* __restrict__ et,
                      unsigned int* __restrict__ cnt, unsigned int* __restrict__ cntd)
{
    int e = blockIdx.x * 256 + threadIdx.x;
    if (e >= NEDGE) return;
    int dst = ei[NEDGE + e];
    atomicAdd(&cnt[(size_t)dst * NREL + et[e]], 1u);
    atomicAdd(&cntd[dst], 1u);
}

// ---- 3-kernel exclusive scan of cntd -> rowptr[NNODES+1] ----
__global__ __launch_bounds__(SCAN_B) void scan1_k(const unsigned int* __restrict__ cntd,
                                                  unsigned int* __restrict__ partial,
                                                  unsigned int* __restrict__ bsum)
{
    __shared__ unsigned int s[SCAN_B];
    int i = blockIdx.x * SCAN_B + threadIdx.x;
    unsigned int v = (i < NNODES) ? cntd[i] : 0u;
    s[threadIdx.x] = v;
    __syncthreads();
    for (int off = 1; off < SCAN_B; off <<= 1) {
        unsigned int t = (threadIdx.x >= off) ? s[threadIdx.x - off] : 0u;
        __syncthreads();
        s[threadIdx.x] += t;
        __syncthreads();
    }
    if (i < NNODES) partial[i] = s[threadIdx.x];          // inclusive within block
    if (threadIdx.x == SCAN_B - 1) bsum[blockIdx.x] = s[SCAN_B - 1];
}

__global__ __launch_bounds__(128) void scan2_k(unsigned int* __restrict__ bsum)
{
    __shared__ unsigned int s[128];
    unsigned int v = (threadIdx.x < SCAN_NB) ? bsum[threadIdx.x] : 0u;
    s[threadIdx.x] = v;
    __syncthreads();
    for (int off = 1; off < 128; off <<= 1) {
        unsigned int t = (threadIdx.x >= off) ? s[threadIdx.x - off] : 0u;
        __syncthreads();
        s[threadIdx.x] += t;
        __syncthreads();
    }
    if (threadIdx.x < SCAN_NB) bsum[threadIdx.x] = s[threadIdx.x];  // inclusive
}

__global__ __launch_bounds__(SCAN_B) void scan3_k(const unsigned int* __restrict__ partial,
                                                  const unsigned int* __restrict__ bsum,
                                                  unsigned int* __restrict__ rowptr)
{
    int i = blockIdx.x * SCAN_B + threadIdx.x;
    if (i >= NNODES) return;
    unsigned int off = (blockIdx.x > 0) ? bsum[blockIdx.x - 1] : 0u;
    rowptr[i + 1] = partial[i] + off;
    if (i == 0) rowptr[0] = 0u;
}

// bucket-fill CSR edge records grouped by dst: 8B each = (src<<4|type, dinv)
__global__ void fill_k(const int* __restrict__ ei, const int* __restrict__ et,
                       const unsigned int* __restrict__ cnt,
                       const unsigned int* __restrict__ rowptr,
                       unsigned int* __restrict__ cursor,
                       float2* __restrict__ erec)
{
    int e = blockIdx.x * 256 + threadIdx.x;
    if (e >= NEDGE) return;
    int dst = ei[NEDGE + e];
    int t = et[e];
    unsigned int c = cnt[(size_t)dst * NREL + t];
    unsigned int pos = rowptr[dst] + atomicAdd(&cursor[dst], 1u);
    float2 r;
    r.x = __uint_as_float(((unsigned)ei[e] << 4) | (unsigned)t);
    r.y = 1.f / (float)(c ? c : 1u);
    erec[pos] = r;
}

// one wave per dst node; 2-edge unroll, packed 8B records, comp in LDS
__global__ __launch_bounds__(256) void gather_k(
    const unsigned short* __restrict__ h, const float* __restrict__ comp,
    const unsigned int* __restrict__ rowptr,
    const float2* __restrict__ erec, float* __restrict__ agg)
{
    __shared__ float scomp[32];
    if (threadIdx.x < 32) scomp[threadIdx.x] = comp[threadIdx.x];
    __syncthreads();
    int node = blockIdx.x * 4 + (threadIdx.x >> 6);
    int lane = threadIdx.x & 63;
    unsigned int p0 = rowptr[node], p1 = rowptr[node + 1];
    f4 accA = (f4){0.f, 0.f, 0.f, 0.f};
    f4 accB = (f4){0.f, 0.f, 0.f, 0.f};
    unsigned int p = p0;
    for (; p + 2 <= p1; p += 2) {
        float2 r0 = erec[p];
        float2 r1 = erec[p + 1];
        unsigned q0 = __float_as_uint(r0.x);
        unsigned q1 = __float_as_uint(r1.x);
        const unsigned short* hp0 = h + (size_t)(q0 >> 4) * 512 + lane * 4;
        const unsigned short* hp1 = h + (size_t)(q1 >> 4) * 512 + lane * 4;
        ushort4 a0 = *(const ushort4*)hp0;
        ushort4 b0 = *(const ushort4*)(hp0 + 256);
        ushort4 a1 = *(const ushort4*)hp1;
        ushort4 b1 = *(const ushort4*)(hp1 + 256);
        float w00 = scomp[(q0 & 15) * 2] * r0.y, w01 = scomp[(q0 & 15) * 2 + 1] * r0.y;
        float w10 = scomp[(q1 & 15) * 2] * r1.y, w11 = scomp[(q1 & 15) * 2 + 1] * r1.y;
        accA.x += w00 * bf2f(a0.x) + w01 * bf2f(b0.x);
        accA.y += w00 * bf2f(a0.y) + w01 * bf2f(b0.y);
        accA.z += w00 * bf2f(a0.z) + w01 * bf2f(b0.z);
        accA.w += w00 * bf2f(a0.w) + w01 * bf2f(b0.w);
        accB.x += w10 * bf2f(a1.x) + w11 * bf2f(b1.x);
        accB.y += w10 * bf2f(a1.y) + w11 * bf2f(b1.y);
        accB.z += w10 * bf2f(a1.z) + w11 * bf2f(b1.z);
        accB.w += w10 * bf2f(a1.w) + w11 * bf2f(b1.w);
    }
    if (p < p1) {
        float2 r0 = erec[p];
        unsigned q0 = __float_as_uint(r0.x);
        const unsigned short* hp0 = h + (size_t)(q0 >> 4) * 512 + lane * 4;
        ushort4 a0 = *(const ushort4*)hp0;
        ushort4 b0 = *(const ushort4*)(hp0 + 256);
        float w00 = scomp[(q0 & 15) * 2] * r0.y, w01 = scomp[(q0 & 15) * 2 + 1] * r0.y;
        accA.x += w00 * bf2f(a0.x) + w01 * bf2f(b0.x);
        accA.y += w00 * bf2f(a0.y) + w01 * bf2f(b0.y);
        accA.z += w00 * bf2f(a0.z) + w01 * bf2f(b0.z);
        accA.w += w00 * bf2f(a0.w) + w01 * bf2f(b0.w);
    }
    accA.x += accB.x; accA.y += accB.y; accA.z += accB.z; accA.w += accB.w;
    *(f4*)(agg + (size_t)node * 256 + lane * 4) = accA;
}

// ONE kernel for all 10 weight transposes (f32 [K,N] -> bf16 [N,K]).
// Block map: proj 384 | b0a 768 | b0b 768 | r0 768 | b1a 256 | b1b 256 |
//            r1 256 | b2a 256 | b2b 256 | r2 256   (total 4224)
__global__ __launch_bounds__(256) void prep_k(
    const float* __restrict__ proj_w,
    const float* __restrict__ b0, const float* __restrict__ r0,
    const float* __restrict__ b1, const float* __restrict__ r1,
    const float* __restrict__ b2, const float* __restrict__ r2,
    unsigned short* __restrict__ wTproj,
    unsigned short* __restrict__ wTb0, unsigned short* __restrict__ wTr0,
    unsigned short* __restrict__ wTb1, unsigned short* __restrict__ wTr1,
    unsigned short* __restrict__ wTb2, unsigned short* __restrict__ wTr2)
{
    int b = blockIdx.x;
    const float* in; unsigned short* out; int K, N, k, nc = 0;
    if (b < 384)                   { in = proj_w;          out = wTproj;          K = 128; N = 768; k = b / 3; nc = b % 3; }
    else if ((b -= 384) < 768)     { in = b0;              out = wTb0;            K = 768; N = 256; k = b; }
    else if ((b -= 768) < 768)     { in = b0 + 768 * 256;  out = wTb0 + 256*768;  K = 768; N = 256; k = b; }
    else if ((b -= 768) < 768)     { in = r0;              out = wTr0;            K = 768; N = 256; k = b; }
    else if ((b -= 768) < 256)     { in = b1;              out = wTb1;            K = 256; N = 256; k = b; }
    else if ((b -= 256) < 256)     { in = b1 + 256 * 256;  out = wTb1 + 256*256;  K = 256; N = 256; k = b; }
    else if ((b -= 256) < 256)     { in = r1;              out = wTr1;            K = 256; N = 256; k = b; }
    else if ((b -= 256) < 256)     { in = b2;              out = wTb2;            K = 256; N = 256; k = b; }
    else if ((b -= 256) < 256)     { in = b2 + 256 * 256;  out = wTb2 + 256*256;  K = 256; N = 256; k = b; }
    else                           { b -= 256; in = r2;    out = wTr2;            K = 256; N = 256; k = b; }
    int n = nc * 256 + threadIdx.x;
    out[(size_t)n * K + k] = f2bf(in[(size_t)k * N + n]);
}

__global__ void bnfin_k(const float* __restrict__ bnsum, const float* __restrict__ gamma,
                        const float* __restrict__ beta, float* __restrict__ bnss)
{
    int c = threadIdx.x;
    float mu = bnsum[c] * (1.f / M_REAL);
    float var = bnsum[256 + c] * (1.f / M_REAL) - mu * mu;
    var = fmaxf(var, 0.f);
    float inv = rsqrtf(var + BN_EPS);
    float sc = gamma[c] * inv;
    bnss[c] = sc;
    bnss[256 + c] = beta[c] - mu * sc;
}

// y(fp32) -> BN scale/shift + relu -> bf16 x_next (or fp32 d_out for last layer)
template<bool LAST>
__global__ __launch_bounds__(256) void apply_k(const float* __restrict__ y,
                                               const float* __restrict__ bnss,
                                               unsigned short* __restrict__ xn,
                                               float* __restrict__ outp)
{
    int i = blockIdx.x * 256 + threadIdx.x;  // 4 elements per thread
    int row = i >> 6;
    int c4 = (i & 63) * 4;
    f4 v = *(const f4*)(y + (size_t)row * 256 + c4);
    f4 sc = *(const f4*)(bnss + c4);
    f4 sh = *(const f4*)(bnss + 256 + c4);
    f4 r;
    r.x = fmaxf(v.x * sc.x + sh.x, 0.f);
    r.y = fmaxf(v.y * sc.y + sh.y, 0.f);
    r.z = fmaxf(v.z * sc.z + sh.z, 0.f);
    r.w = fmaxf(v.w * sc.w + sh.w, 0.f);
    if (LAST) {
        *(f4*)(outp + (size_t)row * 256 + c4) = r;
    } else {
        ushort4 u;
        u.x = f2bf(r.x); u.y = f2bf(r.y); u.z = f2bf(r.z); u.w = f2bf(r.w);
        *(ushort4*)(xn + (size_t)row * 256 + c4) = u;
    }
}

extern "C" void kernel_launch(void* const* d_in, const int* in_sizes, int n_in,
                              void* d_out, int out_size, void* d_ws, size_t ws_size,
                              hipStream_t stream)
{
    const int*   edge_index = (const int*)d_in[0];
    const int*   edge_type  = (const int*)d_in[1];
    const float* emb    = (const float*)d_in[2];
    const float* proj_w = (const float*)d_in[3];
    const float* proj_b = (const float*)d_in[4];
    const float* comp[3]  = {(const float*)d_in[5],  (const float*)d_in[11], (const float*)d_in[17]};
    const float* bases[3] = {(const float*)d_in[6],  (const float*)d_in[12], (const float*)d_in[18]};
    const float* root[3]  = {(const float*)d_in[7],  (const float*)d_in[13], (const float*)d_in[19]};
    const float* biasp[3] = {(const float*)d_in[8],  (const float*)d_in[14], (const float*)d_in[20]};
    const float* gamma[3] = {(const float*)d_in[9],  (const float*)d_in[15], (const float*)d_in[21]};
    const float* beta[3]  = {(const float*)d_in[10], (const float*)d_in[16], (const float*)d_in[22]};

    char* ws = (char*)d_ws;
    size_t off = 0;
    auto alloc = [&](size_t bytes) -> char* {
        char* p = ws + off;
        off = (off + bytes + 255) & ~(size_t)255;
        return p;
    };

    unsigned short* xP  = (unsigned short*)alloc((size_t)M_PAD * 768 * 2);  // proj out; reused as x2
    unsigned short* x1  = (unsigned short*)alloc((size_t)M_PAD * 256 * 2);
    unsigned short* h   = (unsigned short*)alloc((size_t)M_PAD * 512 * 2);  // also y (f32, same bytes)
    float*          agg = (float*)alloc((size_t)M_REAL * 256 * 4);          // x0 aliased inside
    unsigned int*   cnt = (unsigned int*)alloc((size_t)M_REAL * NREL * 4);
    unsigned int*   cntd = (unsigned int*)alloc((size_t)NNODES * 4);
    unsigned int*   rowptr = (unsigned int*)alloc((size_t)(NNODES + 1) * 4);
    unsigned int*   cursor = (unsigned int*)alloc((size_t)NNODES * 4);
    unsigned int*   partial = (unsigned int*)alloc((size_t)NNODES * 4);
    unsigned int*   bsum = (unsigned int*)alloc(128 * 4);
    float2*         erec = (float2*)alloc((size_t)NEDGE * 8);
    unsigned short* wTproj = (unsigned short*)alloc((size_t)768 * 128 * 2);
    unsigned short* wTb0 = (unsigned short*)alloc((size_t)512 * 768 * 2);
    unsigned short* wTr0 = (unsigned short*)alloc((size_t)256 * 768 * 2);
    unsigned short* wTb1 = (unsigned short*)alloc((size_t)512 * 256 * 2);
    unsigned short* wTr1 = (unsigned short*)alloc((size_t)256 * 256 * 2);
    unsigned short* wTb2 = (unsigned short*)alloc((size_t)512 * 256 * 2);
    unsigned short* wTr2 = (unsigned short*)alloc((size_t)256 * 256 * 2);
    float* bns  = (float*)alloc(3 * 512 * 4);  // sums (zeroed)
    float* bnss = (float*)alloc(3 * 512 * 4);  // scale/shift

    unsigned short* x0 = (unsigned short*)agg;  // alias: x0 dead before agg written
    unsigned short* x2 = xP;                    // alias: xP dead before x2 written
    float* y = (float*)h;                       // alias: h dead before y written

    hipMemsetAsync(cnt, 0, (size_t)M_REAL * NREL * 4, stream);
    hipMemsetAsync(cntd, 0, (size_t)NNODES * 4, stream);
    hipMemsetAsync(cursor, 0, (size_t)NNODES * 4, stream);
    hipMemsetAsync(bns, 0, 3 * 512 * 4, stream);

    norm_k<<<M_REAL / 4, 256, 0, stream>>>(emb, x0);
    cnt_k<<<(NEDGE + 255) / 256, 256, 0, stream>>>(edge_index, edge_type, cnt, cntd);
    scan1_k<<<SCAN_NB, SCAN_B, 0, stream>>>(cntd, partial, bsum);
    scan2_k<<<1, 128, 0, stream>>>(bsum);
    scan3_k<<<SCAN_NB, SCAN_B, 0, stream>>>(partial, bsum, rowptr);
    fill_k<<<(NEDGE + 255) / 256, 256, 0, stream>>>(edge_index, edge_type, cnt, rowptr,
                                                    cursor, erec);

    prep_k<<<4224, 256, 0, stream>>>(proj_w, bases[0], root[0], bases[1], root[1],
                                     bases[2], root[2],
                                     wTproj, wTb0, wTr0, wTb1, wTr1, wTb2, wTr2);

    // projection: [50000,128] @ [128,768] + b
    gemm_k<128, 768, true, false><<<8 * RPX * 6, 256, 0, stream>>>(
        x0, wTproj, proj_b, nullptr, nullptr, xP);

    // ---- layer 0 (d_in = 768) ----
    gemm_k<768, 512, false, false><<<8 * RPX * 4, 256, 0, stream>>>(
        xP, wTb0, nullptr, nullptr, nullptr, h);
    gather_k<<<NNODES / 4, 256, 0, stream>>>(h, comp[0], rowptr, erec, agg);
    gemm_k<768, 256, true, true><<<8 * RPX * 2, 256, 0, stream>>>(
        xP, wTr0, biasp[0], agg, bns + 0 * 512, y);
    bnfin_k<<<1, 256, 0, stream>>>(bns + 0 * 512, gamma[0], beta[0], bnss + 0 * 512);
    apply_k<false><<<(M_REAL * 64) / 256, 256, 0, stream>>>(y, bnss + 0 * 512, x1, nullptr);

    // ---- layer 1 (d_in = 256) ----
    gemm_k<256, 512, false, false><<<8 * RPX * 4, 256, 0, stream>>>(
        x1, wTb1, nullptr, nullptr, nullptr, h);
    gather_k<<<NNODES / 4, 256, 0, stream>>>(h, comp[1], rowptr, erec, agg);
    gemm_k<256, 256, true, true><<<8 * RPX * 2, 256, 0, stream>>>(
        x1, wTr1, biasp[1], agg, bns + 1 * 512, y);
    bnfin_k<<<1, 256, 0, stream>>>(bns + 1 * 512, gamma[1], beta[1], bnss + 1 * 512);
    apply_k<false><<<(M_REAL * 64) / 256, 256, 0, stream>>>(y, bnss + 1 * 512, x2, nullptr);

    // ---- layer 2 (d_in = 256) ----
    gemm_k<256, 512, false, false><<<8 * RPX * 4, 256, 0, stream>>>(
        x2, wTb2, nullptr, nullptr, nullptr, h);
    gather_k<<<NNODES / 4, 256, 0, stream>>>(h, comp[2], rowptr, erec, agg);
    gemm_k<256, 256, true, true><<<8 * RPX * 2, 256, 0, stream>>>(
        x2, wTr2, biasp[2], agg, bns + 2 * 512, y);
    bnfin_k<<<1, 256, 0, stream>>>(bns + 2 * 512, gamma[2], beta[2], bnss + 2 * 512);
    apply_k<true><<<(M_REAL * 64) / 256, 256, 0, stream>>>(y, bnss + 2 * 512, nullptr, (float*)d_out);
}